// Round 1
// baseline (631.332 us; speedup 1.0000x reference)
//
#include <hip/hip_runtime.h>
#include <math.h>

#define BATCH 512
#define SEQ   200
#define TOK   10
#define EMB   25
#define HID   64
#define G3    192   // 3*HID

// ---------------------------------------------------------------------------
// Kernel 1: masked-mean embedding bag + step mask
// one 32-lane group per (b,s); lanes 0..24 handle the 25 embedding dims
// ---------------------------------------------------------------------------
__global__ __launch_bounds__(256) void emb_mean_kernel(
    const int* __restrict__ ids_g, const float* __restrict__ emb,
    float* __restrict__ x, float* __restrict__ mask)
{
    int grp  = blockIdx.x * 8 + (threadIdx.x >> 5);
    int lane = threadIdx.x & 31;
    if (grp >= BATCH * SEQ) return;
    const int* ids = ids_g + (size_t)grp * TOK;
    float acc = 0.f;
    int cnt = 0;
    #pragma unroll
    for (int t = 0; t < TOK; t++) {
        int id = ids[t];
        if (id != 0) {
            cnt++;
            if (lane < EMB) acc += emb[(size_t)id * EMB + lane];
        }
    }
    if (lane < EMB)
        x[(size_t)grp * EMB + lane] = cnt ? acc / (float)cnt : 0.f;
    if (lane == 0)
        mask[grp] = (ids[0] != 0) ? 1.f : 0.f;
}

// ---------------------------------------------------------------------------
// Kernel 2: GRU scan, one block per (batch, direction). 192 threads.
// Thread j owns output column j of the 3H recurrent/input projections:
// U[:,j] (64 regs) and W[:,j] (25 regs). h and the x row live in LDS.
// ---------------------------------------------------------------------------
__global__ __launch_bounds__(192) void gru_kernel(
    const float* __restrict__ xg, const float* __restrict__ maskg,
    const float* __restrict__ W_f, const float* __restrict__ U_f, const float* __restrict__ b_f,
    const float* __restrict__ W_b, const float* __restrict__ U_b, const float* __restrict__ b_b,
    float* __restrict__ outg, float* __restrict__ hT)
{
    const int bidx = blockIdx.x;
    const int dir  = bidx >> 9;        // 0 = forward, 1 = backward
    const int b    = bidx & 511;
    const int j    = threadIdx.x;      // 0..191

    const float* W    = dir ? W_b : W_f;
    const float* U    = dir ? U_b : U_f;
    const float* bias = dir ? b_b : b_f;

    float Ucol[HID];
    #pragma unroll
    for (int k = 0; k < HID; k++) Ucol[k] = U[k * G3 + j];
    float Wcol[EMB];
    #pragma unroll
    for (int e = 0; e < EMB; e++) Wcol[e] = W[e * G3 + j];
    const float b0   = bias[j];        // input-proj bias  b[0][j]
    const float brec = bias[G3 + j];   // recurrent bias   b[1][j]

    __shared__ float xs[SEQ * EMB];    // 20 KB: this batch's x row
    __shared__ float ms[SEQ];
    __shared__ float hsh[HID];
    __shared__ float recs[G3];
    __shared__ float xps[G3];

    const float* xrow = xg + (size_t)b * (SEQ * EMB);
    for (int i = j; i < SEQ * EMB; i += 192) xs[i] = xrow[i];
    for (int i = j; i < SEQ; i += 192) ms[i] = maskg[(size_t)b * SEQ + i];
    if (j < HID) hsh[j] = 0.f;
    __syncthreads();

    for (int step = 0; step < SEQ; step++) {
        const int s = dir ? (SEQ - 1 - step) : step;

        // rec[j] = b_rec[j] + h . U[:,j]   (4-way split accumulators for ILP)
        float a0 = brec, a1 = 0.f, a2 = 0.f, a3 = 0.f;
        #pragma unroll
        for (int k = 0; k < HID; k += 4) {
            a0 = fmaf(hsh[k + 0], Ucol[k + 0], a0);
            a1 = fmaf(hsh[k + 1], Ucol[k + 1], a1);
            a2 = fmaf(hsh[k + 2], Ucol[k + 2], a2);
            a3 = fmaf(hsh[k + 3], Ucol[k + 3], a3);
        }
        float rec = (a0 + a1) + (a2 + a3);

        // xp[j] = b0[j] + x[s] . W[:,j]
        const float* xr = xs + s * EMB;
        float p0 = b0, p1 = 0.f, p2 = 0.f, p3 = 0.f;
        #pragma unroll
        for (int e = 0; e < 24; e += 4) {
            p0 = fmaf(xr[e + 0], Wcol[e + 0], p0);
            p1 = fmaf(xr[e + 1], Wcol[e + 1], p1);
            p2 = fmaf(xr[e + 2], Wcol[e + 2], p2);
            p3 = fmaf(xr[e + 3], Wcol[e + 3], p3);
        }
        p0 = fmaf(xr[24], Wcol[24], p0);
        float xp = (p0 + p1) + (p2 + p3);

        recs[j] = rec;
        xps[j]  = xp;
        __syncthreads();

        if (j < HID) {
            float hold = hsh[j];
            float z  = 1.f / (1.f + expf(-(xps[j]           + recs[j])));
            float r  = 1.f / (1.f + expf(-(xps[HID + j]     + recs[HID + j])));
            float hh = tanhf(xps[2 * HID + j] + r * recs[2 * HID + j]);
            float hn = z * hold + (1.f - z) * hh;
            hn = (ms[s] != 0.f) ? hn : hold;
            hsh[j] = hn;
            outg[((size_t)b * SEQ + s) * (2 * HID) + dir * HID + j] = hn;
        }
        __syncthreads();
    }
    if (dir == 0 && j < HID) hT[(size_t)b * HID + j] = hsh[j];
}

// ---------------------------------------------------------------------------
// Kernel 3: attention pooling. One block (256 threads = 4 waves) per batch.
// ---------------------------------------------------------------------------
__global__ __launch_bounds__(256) void attn_kernel(
    const float* __restrict__ outg, const float* __restrict__ maskg,
    const float* __restrict__ hT,
    const float* __restrict__ W_k, const float* __restrict__ b_k,
    const float* __restrict__ W_q, const float* __restrict__ b_q,
    const float* __restrict__ W_e, const float* __restrict__ b_e,
    float* __restrict__ ctx)
{
    const int b   = blockIdx.x;
    const int tid = threadIdx.x;

    __shared__ float Wks[2 * HID * HID];   // 128x64 = 32 KB
    __shared__ float qs[HID];
    __shared__ float es[SEQ];

    for (int i = tid; i < 2 * HID * HID; i += 256) Wks[i] = W_k[i];
    if (tid < HID) {
        float q = b_q[tid];
        const float* hrow = hT + (size_t)b * HID;
        #pragma unroll 8
        for (int i = 0; i < HID; i++) q = fmaf(hrow[i], W_q[i * HID + tid], q);
        qs[tid] = q;
    }
    __syncthreads();

    const int wave = tid >> 6;
    const int lane = tid & 63;
    const float bk = b_k[lane];
    const float we = W_e[lane];
    const float be = b_e[0];

    // phase 1: scores e[s]; each wave takes every 4th s
    for (int s = wave; s < SEQ; s += 4) {
        const float* orow = outg + ((size_t)b * SEQ + s) * (2 * HID);
        float a0 = 0.f, a1 = 0.f, a2 = 0.f, a3 = 0.f;
        #pragma unroll
        for (int i = 0; i < 2 * HID; i += 4) {
            a0 = fmaf(orow[i + 0], Wks[(i + 0) * HID + lane], a0);
            a1 = fmaf(orow[i + 1], Wks[(i + 1) * HID + lane], a1);
            a2 = fmaf(orow[i + 2], Wks[(i + 2) * HID + lane], a2);
            a3 = fmaf(orow[i + 3], Wks[(i + 3) * HID + lane], a3);
        }
        float t = tanhf(((a0 + a1) + (a2 + a3)) + bk + qs[lane]) * we;
        #pragma unroll
        for (int off = 32; off > 0; off >>= 1) t += __shfl_down(t, off);
        if (lane == 0) {
            float pen = (maskg[(size_t)b * SEQ + s] != 0.f) ? 0.f : -1e9f;
            es[s] = t + be + pen;
        }
    }
    __syncthreads();

    // phase 2: softmax over the 200 scores (single wave)
    if (tid < 64) {
        float mx = -1e30f;
        for (int s2 = tid; s2 < SEQ; s2 += 64) mx = fmaxf(mx, es[s2]);
        #pragma unroll
        for (int off = 32; off > 0; off >>= 1) mx = fmaxf(mx, __shfl_xor(mx, off));
        float sum = 0.f;
        for (int s2 = tid; s2 < SEQ; s2 += 64) {
            float w = expf(es[s2] - mx);
            es[s2] = w;
            sum += w;
        }
        #pragma unroll
        for (int off = 32; off > 0; off >>= 1) sum += __shfl_xor(sum, off);
        float inv = 1.f / sum;
        for (int s2 = tid; s2 < SEQ; s2 += 64) es[s2] *= inv;
    }
    __syncthreads();

    // phase 3: context[j] = sum_s w[s] * out[b,s,j]
    if (tid < 2 * HID) {
        const int jj = tid;
        float a0 = 0.f, a1 = 0.f;
        for (int s2 = 0; s2 < SEQ; s2 += 2) {
            a0 = fmaf(es[s2],     outg[((size_t)b * SEQ + s2)     * (2 * HID) + jj], a0);
            a1 = fmaf(es[s2 + 1], outg[((size_t)b * SEQ + s2 + 1) * (2 * HID) + jj], a1);
        }
        ctx[(size_t)b * (2 * HID) + jj] = a0 + a1;
    }
}

// ---------------------------------------------------------------------------
extern "C" void kernel_launch(void* const* d_in, const int* in_sizes, int n_in,
                              void* d_out, int out_size, void* d_ws, size_t ws_size,
                              hipStream_t stream) {
    const int*   ids = (const int*)  d_in[0];
    const float* emb = (const float*)d_in[1];
    const float* W_f = (const float*)d_in[2];
    const float* U_f = (const float*)d_in[3];
    const float* b_f = (const float*)d_in[4];
    const float* W_b = (const float*)d_in[5];
    const float* U_b = (const float*)d_in[6];
    const float* b_b = (const float*)d_in[7];
    const float* W_k = (const float*)d_in[8];
    const float* b_k = (const float*)d_in[9];
    const float* W_q = (const float*)d_in[10];
    const float* b_q = (const float*)d_in[11];
    const float* W_e = (const float*)d_in[12];
    const float* b_e = (const float*)d_in[13];

    float* ws   = (float*)d_ws;
    // workspace layout (floats):
    //   x    : [0, 2'560'000)                 (B*S*E)
    //   mask : [2'560'000, 2'662'400)         (B*S)
    //   out  : [2'662'400, 15'769'600)        (B*S*2H)
    //   hT   : [15'769'600, 15'802'368)       (B*H)
    float* x    = ws;
    float* mask = ws + 2560000;
    float* out  = ws + 2662400;
    float* hT   = ws + 15769600;

    emb_mean_kernel<<<(BATCH * SEQ) / 8, 256, 0, stream>>>(ids, emb, x, mask);
    gru_kernel<<<1024, 192, 0, stream>>>(x, mask, W_f, U_f, b_f,
                                         W_b, U_b, b_b, out, hT);
    attn_kernel<<<BATCH, 256, 0, stream>>>(out, mask, hT, W_k, b_k,
                                           W_q, b_q, W_e, b_e, (float*)d_out);
}

// Round 2
// 466.302 us; speedup vs baseline: 1.3539x; 1.3539x over previous
//
#include <hip/hip_runtime.h>
#include <math.h>

#define BATCH 512
#define SEQ   200
#define TOK   10
#define EMB   25
#define HID   64
#define G3    192   // 3*HID

__device__ __forceinline__ float fast_sigmoid(float t) {
    float e = __expf(-t);
    return __builtin_amdgcn_rcpf(1.f + e);
}
__device__ __forceinline__ float fast_tanh(float t) {
    float e2 = __expf(2.f * t);
    return 1.f - 2.f * __builtin_amdgcn_rcpf(e2 + 1.f);
}

// ---------------------------------------------------------------------------
// Kernel 1: masked-mean embedding bag + step mask
// one 32-lane group per (b,s); lanes 0..24 handle the 25 embedding dims
// ---------------------------------------------------------------------------
__global__ __launch_bounds__(256) void emb_mean_kernel(
    const int* __restrict__ ids_g, const float* __restrict__ emb,
    float* __restrict__ x, float* __restrict__ mask)
{
    int grp  = blockIdx.x * 8 + (threadIdx.x >> 5);
    int lane = threadIdx.x & 31;
    if (grp >= BATCH * SEQ) return;
    const int* ids = ids_g + (size_t)grp * TOK;
    float acc = 0.f;
    int cnt = 0;
    #pragma unroll
    for (int t = 0; t < TOK; t++) {
        int id = ids[t];
        if (id != 0) {
            cnt++;
            if (lane < EMB) acc += emb[(size_t)id * EMB + lane];
        }
    }
    if (lane < EMB)
        x[(size_t)grp * EMB + lane] = cnt ? acc / (float)cnt : 0.f;
    if (lane == 0)
        mask[grp] = (ids[0] != 0) ? 1.f : 0.f;
}

// ---------------------------------------------------------------------------
// Kernel 2: GRU scan — ONE WAVE per (batch, direction). 64 threads.
// Lane j owns all three gate columns (z,r,h) of U and W in registers
// (~267 VGPRs; __launch_bounds__(64,1) permits up to 512). Per step:
//   - x-dot (broadcast LDS reads of x row, per-lane W regs)
//   - h-dot (broadcast LDS reads of h[64], per-lane U regs)
//   - activation entirely in registers (no LDS round-trip, no barriers)
//   - hn broadcast back via 1 ds_write; wave-lockstep + in-order DS pipe
//     + wave_barrier() compiler fences make this safe without s_barrier,
//     so no vmcnt(0) drain of the global store on the critical path.
// ---------------------------------------------------------------------------
__global__ __launch_bounds__(64, 1) void gru_kernel(
    const float* __restrict__ xg, const float* __restrict__ maskg,
    const float* __restrict__ W_f, const float* __restrict__ U_f, const float* __restrict__ b_f,
    const float* __restrict__ W_b, const float* __restrict__ U_b, const float* __restrict__ b_b,
    float* __restrict__ outg, float* __restrict__ hT)
{
    const int bidx = blockIdx.x;
    const int dir  = bidx >> 9;        // 0 = forward, 1 = backward
    const int b    = bidx & 511;
    const int j    = threadIdx.x;      // 0..63

    const float* W    = dir ? W_b : W_f;
    const float* U    = dir ? U_b : U_f;
    const float* bias = dir ? b_b : b_f;

    // per-lane weight columns: j (z-gate), 64+j (r-gate), 128+j (h-gate)
    float Uz[HID], Ur[HID], Uh[HID];
    #pragma unroll
    for (int k = 0; k < HID; k++) {
        Uz[k] = U[k * G3 + j];
        Ur[k] = U[k * G3 + HID + j];
        Uh[k] = U[k * G3 + 2 * HID + j];
    }
    float Wz[EMB], Wr[EMB], Wh[EMB];
    #pragma unroll
    for (int e = 0; e < EMB; e++) {
        Wz[e] = W[e * G3 + j];
        Wr[e] = W[e * G3 + HID + j];
        Wh[e] = W[e * G3 + 2 * HID + j];
    }
    const float bz0 = bias[j];
    const float br0 = bias[HID + j];
    const float bh0 = bias[2 * HID + j];
    const float bzr = bias[G3 + j];
    const float brr = bias[G3 + HID + j];
    const float bhr = bias[G3 + 2 * HID + j];

    __shared__ float xs[SEQ * EMB];    // 20 KB: this batch's x rows
    __shared__ float ms[SEQ];
    __shared__ float hs[HID];

    // cooperative staging (vectorized; 5000 floats = 1250 float4)
    {
        const float4* xrow4 = (const float4*)(xg + (size_t)b * (SEQ * EMB));
        float4* xs4 = (float4*)xs;
        for (int i = j; i < (SEQ * EMB) / 4; i += 64) xs4[i] = xrow4[i];
        for (int i = j; i < SEQ; i += 64) ms[i] = maskg[(size_t)b * SEQ + i];
        hs[j] = 0.f;
    }
    __syncthreads();   // once, before the loop (single wave: cheap)

    float h = 0.f;
    float* orow_base = outg + (size_t)b * SEQ * (2 * HID) + dir * HID + j;

    for (int step = 0; step < SEQ; step++) {
        const int s = dir ? (SEQ - 1 - step) : step;

        // input projection: xp_g[j] = b0_g[j] + x[s] . W_g[:,j]
        const float* xr = xs + s * EMB;
        float pz = bz0, pr = br0, ph = bh0;
        #pragma unroll
        for (int e = 0; e < EMB; e++) {
            float xv = xr[e];
            pz = fmaf(xv, Wz[e], pz);
            pr = fmaf(xv, Wr[e], pr);
            ph = fmaf(xv, Wh[e], ph);
        }

        // recurrent projection: rec_g[j] = brec_g[j] + h . U_g[:,j]
        float az = bzr, ar = brr, ah = bhr;
        #pragma unroll
        for (int k = 0; k < HID; k++) {
            float hk = hs[k];
            az = fmaf(hk, Uz[k], az);
            ar = fmaf(hk, Ur[k], ar);
            ah = fmaf(hk, Uh[k], ah);
        }

        float z  = fast_sigmoid(pz + az);
        float r  = fast_sigmoid(pr + ar);
        float hh = fast_tanh(ph + r * ah);
        float hn = z * h + (1.f - z) * hh;
        hn = (ms[s] != 0.f) ? hn : h;
        h = hn;

        // broadcast new h; fences keep (reads_s) < (write_s) < (reads_{s+1})
        __builtin_amdgcn_wave_barrier();
        hs[j] = hn;
        __builtin_amdgcn_wave_barrier();

        orow_base[(size_t)s * (2 * HID)] = hn;   // fire-and-forget
    }
    if (dir == 0) hT[(size_t)b * HID + j] = h;
}

// ---------------------------------------------------------------------------
// Kernel 3: attention pooling. One block (256 threads = 4 waves) per batch.
// ---------------------------------------------------------------------------
__global__ __launch_bounds__(256) void attn_kernel(
    const float* __restrict__ outg, const float* __restrict__ maskg,
    const float* __restrict__ hT,
    const float* __restrict__ W_k, const float* __restrict__ b_k,
    const float* __restrict__ W_q, const float* __restrict__ b_q,
    const float* __restrict__ W_e, const float* __restrict__ b_e,
    float* __restrict__ ctx)
{
    const int b   = blockIdx.x;
    const int tid = threadIdx.x;

    __shared__ float Wks[2 * HID * HID];   // 128x64 = 32 KB
    __shared__ float qs[HID];
    __shared__ float es[SEQ];

    for (int i = tid; i < 2 * HID * HID; i += 256) Wks[i] = W_k[i];
    if (tid < HID) {
        float q = b_q[tid];
        const float* hrow = hT + (size_t)b * HID;
        #pragma unroll 8
        for (int i = 0; i < HID; i++) q = fmaf(hrow[i], W_q[i * HID + tid], q);
        qs[tid] = q;
    }
    __syncthreads();

    const int wave = tid >> 6;
    const int lane = tid & 63;
    const float bk = b_k[lane];
    const float we = W_e[lane];
    const float be = b_e[0];

    // phase 1: scores e[s]; each wave takes every 4th s
    for (int s = wave; s < SEQ; s += 4) {
        const float* orow = outg + ((size_t)b * SEQ + s) * (2 * HID);
        float a0 = 0.f, a1 = 0.f, a2 = 0.f, a3 = 0.f;
        #pragma unroll
        for (int i = 0; i < 2 * HID; i += 4) {
            a0 = fmaf(orow[i + 0], Wks[(i + 0) * HID + lane], a0);
            a1 = fmaf(orow[i + 1], Wks[(i + 1) * HID + lane], a1);
            a2 = fmaf(orow[i + 2], Wks[(i + 2) * HID + lane], a2);
            a3 = fmaf(orow[i + 3], Wks[(i + 3) * HID + lane], a3);
        }
        float t = tanhf(((a0 + a1) + (a2 + a3)) + bk + qs[lane]) * we;
        #pragma unroll
        for (int off = 32; off > 0; off >>= 1) t += __shfl_down(t, off);
        if (lane == 0) {
            float pen = (maskg[(size_t)b * SEQ + s] != 0.f) ? 0.f : -1e9f;
            es[s] = t + be + pen;
        }
    }
    __syncthreads();

    // phase 2: softmax over the 200 scores (single wave)
    if (tid < 64) {
        float mx = -1e30f;
        for (int s2 = tid; s2 < SEQ; s2 += 64) mx = fmaxf(mx, es[s2]);
        #pragma unroll
        for (int off = 32; off > 0; off >>= 1) mx = fmaxf(mx, __shfl_xor(mx, off));
        float sum = 0.f;
        for (int s2 = tid; s2 < SEQ; s2 += 64) {
            float w = expf(es[s2] - mx);
            es[s2] = w;
            sum += w;
        }
        #pragma unroll
        for (int off = 32; off > 0; off >>= 1) sum += __shfl_xor(sum, off);
        float inv = 1.f / sum;
        for (int s2 = tid; s2 < SEQ; s2 += 64) es[s2] *= inv;
    }
    __syncthreads();

    // phase 3: context[j] = sum_s w[s] * out[b,s,j]
    if (tid < 2 * HID) {
        const int jj = tid;
        float a0 = 0.f, a1 = 0.f;
        for (int s2 = 0; s2 < SEQ; s2 += 2) {
            a0 = fmaf(es[s2],     outg[((size_t)b * SEQ + s2)     * (2 * HID) + jj], a0);
            a1 = fmaf(es[s2 + 1], outg[((size_t)b * SEQ + s2 + 1) * (2 * HID) + jj], a1);
        }
        ctx[(size_t)b * (2 * HID) + jj] = a0 + a1;
    }
}

// ---------------------------------------------------------------------------
extern "C" void kernel_launch(void* const* d_in, const int* in_sizes, int n_in,
                              void* d_out, int out_size, void* d_ws, size_t ws_size,
                              hipStream_t stream) {
    const int*   ids = (const int*)  d_in[0];
    const float* emb = (const float*)d_in[1];
    const float* W_f = (const float*)d_in[2];
    const float* U_f = (const float*)d_in[3];
    const float* b_f = (const float*)d_in[4];
    const float* W_b = (const float*)d_in[5];
    const float* U_b = (const float*)d_in[6];
    const float* b_b = (const float*)d_in[7];
    const float* W_k = (const float*)d_in[8];
    const float* b_k = (const float*)d_in[9];
    const float* W_q = (const float*)d_in[10];
    const float* b_q = (const float*)d_in[11];
    const float* W_e = (const float*)d_in[12];
    const float* b_e = (const float*)d_in[13];

    float* ws   = (float*)d_ws;
    // workspace layout (floats):
    //   x    : [0, 2'560'000)                 (B*S*E)
    //   mask : [2'560'000, 2'662'400)         (B*S)
    //   out  : [2'662'400, 15'769'600)        (B*S*2H)
    //   hT   : [15'769'600, 15'802'368)       (B*H)
    float* x    = ws;
    float* mask = ws + 2560000;
    float* out  = ws + 2662400;
    float* hT   = ws + 15769600;

    emb_mean_kernel<<<(BATCH * SEQ) / 8, 256, 0, stream>>>(ids, emb, x, mask);
    gru_kernel<<<1024, 64, 0, stream>>>(x, mask, W_f, U_f, b_f,
                                        W_b, U_b, b_b, out, hT);
    attn_kernel<<<BATCH, 256, 0, stream>>>(out, mask, hT, W_k, b_k,
                                           W_q, b_q, W_e, b_e, (float*)d_out);
}